// Round 1
// baseline (21170.676 us; speedup 1.0000x reference)
//
#include <hip/hip_runtime.h>
#include <hip/hip_bf16.h>
#include <hip/hip_fp16.h>

// Problem constants (fixed by the reference)
#define FDIM 128      // F_IN == H == 128
#define G4H  512      // 4*H

typedef float f32x4 __attribute__((ext_vector_type(4)));
typedef _Float16 f16x8 __attribute__((ext_vector_type(8)));

union frag_cast { f32x4 f; f16x8 h; };

// LDS-only barrier: does NOT drain vmcnt (global ops stay in flight).
#define LDS_BARRIER() asm volatile("s_waitcnt lgkmcnt(0)\n\ts_barrier" ::: "memory")

#define AS1 __attribute__((address_space(1)))
#define AS3 __attribute__((address_space(3)))
// Async global->LDS, 16B/lane: LDS dst = uniform base + lane*16. (unused by v16 LSTM)
__device__ __forceinline__ void load_lds16(const float* g, float* l) {
    __builtin_amdgcn_global_load_lds((const AS1 unsigned int*)g,
                                     (AS3 unsigned int*)l, 16, 0, 0);
}

// ---------------------------------------------------------------------------
// degree / normalization
// ---------------------------------------------------------------------------
__global__ void deg_kernel(const int* __restrict__ ei, int* __restrict__ deg, int E) {
    int e = blockIdx.x * 256 + threadIdx.x;
    if (e < E) atomicAdd(&deg[ei[E + e]], 1);
}

__global__ void dinv_kernel(const int* __restrict__ deg, float* __restrict__ dinv, int N) {
    int n = blockIdx.x * 256 + threadIdx.x;
    if (n < N) dinv[n] = rsqrtf((float)(deg[n] + 1));   // +1 self-loop
}

// ---------------------------------------------------------------------------
// CSR build: exclusive scan of deg (1024 thr x 20 nodes), then edge scatter.
// ---------------------------------------------------------------------------
__global__ __launch_bounds__(1024) void scan_kernel(const int* __restrict__ deg,
                                                    int* __restrict__ rs,
                                                    int* __restrict__ cursor,
                                                    int N, int E) {
    __shared__ int buf[2][1024];
    const int t = threadIdx.x;
    const int base = t * 20;
    int loc[20]; int s = 0;
    #pragma unroll
    for (int i = 0; i < 20; ++i) {
        int n = base + i;
        int d = (n < N) ? deg[n] : 0;
        loc[i] = s; s += d;
    }
    buf[0][t] = s; __syncthreads();
    int pb = 0;
    for (int off = 1; off < 1024; off <<= 1) {
        int v = buf[pb][t] + ((t >= off) ? buf[pb][t - off] : 0);
        buf[pb ^ 1][t] = v; pb ^= 1; __syncthreads();
    }
    int pre = (t > 0) ? buf[pb][t - 1] : 0;   // exclusive prefix
    #pragma unroll
    for (int i = 0; i < 20; ++i) {
        int n = base + i;
        if (n < N) { int v = pre + loc[i]; rs[n] = v; cursor[n] = v; }
    }
    if (t == 0) rs[N] = E;
}

__global__ void scatter_kernel(const int* __restrict__ ei, int* __restrict__ cursor,
                               int* __restrict__ csr_src, int E) {
    int e = blockIdx.x * 256 + threadIdx.x;
    if (e >= E) return;
    int s = ei[e], d = ei[E + e];
    int pos = atomicAdd(&cursor[d], 1);
    csr_src[pos] = s;
}

// ---------------------------------------------------------------------------
// C[M x 128] = A[M x 128] @ B[128 x 128]   (B is K-major: B[k*128 + j])
// ---------------------------------------------------------------------------
__global__ __launch_bounds__(256) void gemm_nn(const float* __restrict__ A,
                                               const float* __restrict__ B,
                                               float* __restrict__ C, int M) {
    __shared__ float Bl[64 * 132];
    __shared__ float Al[32][FDIM];
    const int tid = threadIdx.x;
    const int row0 = blockIdx.x * 32;

    for (int i = tid * 4; i < 32 * FDIM; i += 1024) {
        int r = i >> 7, k = i & 127;
        int row = row0 + r;
        float4 v = make_float4(0.f, 0.f, 0.f, 0.f);
        if (row < M) v = *(const float4*)(A + (size_t)row * FDIM + k);
        *(float4*)&Al[r][k] = v;
    }

    const int jg = tid & 31, rg = tid >> 5;
    float acc[4][4] = {};

    for (int kh = 0; kh < 2; ++kh) {
        __syncthreads();
        for (int i = tid * 4; i < 64 * FDIM; i += 1024) {
            int k = i >> 7, j = i & 127;
            *(float4*)&Bl[k * 132 + j] = *(const float4*)(B + (size_t)(kh * 64 + k) * FDIM + j);
        }
        __syncthreads();
        #pragma unroll 4
        for (int k = 0; k < 64; ++k) {
            float4 b4 = *(const float4*)&Bl[k * 132 + jg * 4];
            #pragma unroll
            for (int rr = 0; rr < 4; ++rr) {
                float a = Al[rg * 4 + rr][kh * 64 + k];
                acc[rr][0] += a * b4.x; acc[rr][1] += a * b4.y;
                acc[rr][2] += a * b4.z; acc[rr][3] += a * b4.w;
            }
        }
    }
    #pragma unroll
    for (int rr = 0; rr < 4; ++rr) {
        int row = row0 + rg * 4 + rr;
        if (row < M) {
            float4 v = make_float4(acc[rr][0], acc[rr][1], acc[rr][2], acc[rr][3]);
            *(float4*)(C + (size_t)row * FDIM + jg * 4) = v;
        }
    }
}

// ---------------------------------------------------------------------------
// xg[M x 512] = A[M x 128] @ B^T  (+ b_ih + b_hh), B is [512 x 128] row-major.
// Output layout [step][gate*128 + j].
// ---------------------------------------------------------------------------
__global__ __launch_bounds__(256) void gemm_nt_xg(const float* __restrict__ A,
                                                  const float* __restrict__ B,
                                                  const float* __restrict__ bih,
                                                  const float* __restrict__ bhh,
                                                  float* __restrict__ C, int M) {
    __shared__ float Bl[64 * 132];
    __shared__ float Al[32][FDIM];
    const int tid = threadIdx.x;
    const int row0 = blockIdx.x * 32;
    const int chunk = blockIdx.y;

    for (int i = tid * 4; i < 32 * FDIM; i += 1024) {
        int r = i >> 7, k = i & 127;
        int row = row0 + r;
        float4 v = make_float4(0.f, 0.f, 0.f, 0.f);
        if (row < M) v = *(const float4*)(A + (size_t)row * FDIM + k);
        *(float4*)&Al[r][k] = v;
    }

    const int jg = tid & 31, rg = tid >> 5;
    float acc[4][4] = {};

    for (int kh = 0; kh < 2; ++kh) {
        __syncthreads();
        for (int i = tid * 4; i < 128 * 64; i += 1024) {
            int g = i >> 6, kl = i & 63;
            float4 v = *(const float4*)(B + (size_t)(chunk * 128 + g) * FDIM + kh * 64 + kl);
            Bl[(kl + 0) * 132 + g] = v.x;
            Bl[(kl + 1) * 132 + g] = v.y;
            Bl[(kl + 2) * 132 + g] = v.z;
            Bl[(kl + 3) * 132 + g] = v.w;
        }
        __syncthreads();
        #pragma unroll 4
        for (int k = 0; k < 64; ++k) {
            float4 b4 = *(const float4*)&Bl[k * 132 + jg * 4];
            #pragma unroll
            for (int rr = 0; rr < 4; ++rr) {
                float a = Al[rg * 4 + rr][kh * 64 + k];
                acc[rr][0] += a * b4.x; acc[rr][1] += a * b4.y;
                acc[rr][2] += a * b4.z; acc[rr][3] += a * b4.w;
            }
        }
    }
    const int col0 = chunk * 128 + jg * 4;
    float4 bsum = make_float4(bih[col0 + 0] + bhh[col0 + 0],
                              bih[col0 + 1] + bhh[col0 + 1],
                              bih[col0 + 2] + bhh[col0 + 2],
                              bih[col0 + 3] + bhh[col0 + 3]);
    #pragma unroll
    for (int rr = 0; rr < 4; ++rr) {
        int row = row0 + rg * 4 + rr;
        if (row < M) {
            float4 v = make_float4(acc[rr][0] + bsum.x, acc[rr][1] + bsum.y,
                                   acc[rr][2] + bsum.z, acc[rr][3] + bsum.w);
            *(float4*)(C + (size_t)row * G4H + col0) = v;
        }
    }
}

// ---------------------------------------------------------------------------
// Fused GCN aggregation (CSR gather): one wave per node, registers, one write.
// ---------------------------------------------------------------------------
__global__ __launch_bounds__(256) void agg_gather(const float* __restrict__ y,
                                                  const int* __restrict__ rs,
                                                  const int* __restrict__ csr_src,
                                                  const float* __restrict__ dinv,
                                                  const float* __restrict__ bias,
                                                  float* __restrict__ o, int N) {
    const int node = blockIdx.x * 4 + (threadIdx.x >> 6);
    if (node >= N) return;
    const int lane = threadIdx.x & 63;
    const int beg = rs[node], end = rs[node + 1];
    const float dn = dinv[node];

    float2 yv = *(const float2*)(y + (size_t)node * FDIM + lane * 2);
    float2 acc = make_float2(yv.x * dn * dn, yv.y * dn * dn);

    for (int base = beg; base < end; base += 64) {
        int cnt = end - base; if (cnt > 64) cnt = 64;
        int msrc = 0; float mnrm = 0.f;
        if (lane < cnt) {
            msrc = csr_src[base + lane];
            mnrm = dinv[msrc] * dn;
        }
        for (int j = 0; j < cnt; ++j) {
            int s = __shfl(msrc, j);
            float nr = __shfl(mnrm, j);
            float2 v = *(const float2*)(y + (size_t)s * FDIM + lane * 2);
            acc.x += v.x * nr;
            acc.y += v.y * nr;
        }
    }
    float2 b = *(const float2*)(bias + lane * 2);
    acc.x = fmaxf(acc.x + b.x, 0.f);
    acc.y = fmaxf(acc.y + b.y, 0.f);
    *(float2*)(o + (size_t)node * FDIM + lane * 2) = acc;
}

// ---------------------------------------------------------------------------
// Prepack w_hh [512 x 128] fp32 into fp16 MFMA A-fragments (8-group layout).
// dword idx = (((w8*4+rt)*4+kt)*64 + lane)*4 + d
//   group w8 (0..7): rows [64*w8, 64*w8+64); row-tile rt (0..3);
//   lane: m = lane&15, q = lane>>4; row r = 64*w8+16rt+m; k = 32kt+8q+{2d,2d+1}.
// v16 LSTM indexes it as wp4[((w*8+rt8)*4+kt)*64+lane]  (w = wave/gate 0..3,
// rt8 = 0..7), which covers rows 128w+16*rt8+m — same packing, re-grouped.
// ---------------------------------------------------------------------------
__global__ void pack_whh(const float* __restrict__ whh, float* __restrict__ whp, int n) {
    int i = blockIdx.x * 256 + threadIdx.x;   // n = 32768 dwords
    if (i >= n) return;
    int d = i & 3, fi = i >> 2;
    int lane = fi & 63, kt = (fi >> 6) & 3, rt = (fi >> 8) & 3, w = fi >> 10;
    int m = lane & 15, q = lane >> 4;
    int r = 64 * w + 16 * rt + m;
    int k = 32 * kt + 8 * q + 2 * d;
    __half lo = __float2half(whh[r * FDIM + k]);
    __half hi = __float2half(whh[r * FDIM + k + 1]);
    unsigned u = ((unsigned)__half_as_ushort(hi) << 16) | (unsigned)__half_as_ushort(lo);
    whp[i] = __uint_as_float(u);
}

// ---------------------------------------------------------------------------
// LSTM v16: 4-wave gate-parallel, register-resident weights, ONE barrier/step.
//
// Wave w (0..3) owns gate w (rows 128w..128w+127 of w_hh) as 32 AGPR-pinned
// fp16 A-fragments. Per step:
//   phase A: 32 MFMAs (8 chains x depth 4), 8 predicated ds_write_b128 of the
//            gate pre-activations into double-buffered gl[step&1][gate][j].
//   one LDS barrier (lgkmcnt-only; global loads stay in flight).
//   phase B: ALL 4 waves redundantly: lane l owns h[2l],h[2l+1]; 4x
//            ds_read_b64 (2-way banks = free), activations, c in registers
//            (replicated per wave - deterministic => consistent), pack h to
//            one fp16 dword, rebuild own B-fragments with 16 wave-local
//            ds_bpermute (NO cross-wave h distribution, NO second barrier).
// xg streams global->register 2-deep ring (compiler-counted vmcnt; ~2 steps
// = ~1200 cyc prefetch distance). hs stored by the q==w quarter of each wave.
// Rationale: v9's 1580 cyc/step was dominated by the two cross-wave LDS
// round-trips + 8-wave barriers; this removes one round-trip entirely and
// makes the other single-barrier + double-buffered.
// ---------------------------------------------------------------------------
__global__ void __launch_bounds__(256, 1)
lstm_kernel(const float* __restrict__ xg, const float* __restrict__ whp,
            float* __restrict__ hs, int T) {
    __shared__ __align__(16) float gl[2][4][132];   // [buf][gate][j(+pad)]
    const int t    = threadIdx.x;
    const int w    = t >> 6;        // wave 0..3 == gate index
    const int lane = t & 63;
    const int q    = lane >> 4;     // k-quad / C row-quad
    const int n    = lane & 15;     // C column -> row-tile selector on write
    const int jj   = 2 * lane;      // this lane's two hidden indices jj, jj+1

    // ---- A-fragments: aw[rt][kt] covers rows 128w+16rt+n, k=32kt+8q+{0..7}
    f16x8 aw[8][4];
    {
        const f32x4* wp4 = (const f32x4*)whp;
        #pragma unroll
        for (int rt = 0; rt < 8; ++rt) {
            #pragma unroll
            for (int kt = 0; kt < 4; ++kt) {
                frag_cast fc;
                fc.f = wp4[((w * 8 + rt) * 4 + kt) * 64 + lane];
                f16x8 tmp = fc.h;
                asm volatile("" : "=a"(aw[rt][kt]) : "0"(tmp));  // pin to AGPR class
            }
        }
    }

    const f32x4 vzero = {0.f, 0.f, 0.f, 0.f};

    // ---- xg prefetch ring (2 slots), per-lane register loads
    const float* pxl = xg + jj;
    float2 xfA[4], xfB[4];
    #pragma unroll
    for (int g = 0; g < 4; ++g) xfA[g] = *(const float2*)(pxl + (size_t)0 * G4H + g * FDIM);
    #pragma unroll
    for (int g = 0; g < 4; ++g) xfB[g] = *(const float2*)(pxl + (size_t)1 * G4H + g * FDIM);

    // ---- state
    f16x8 bf[4];                 // B-fragments built from h_{t-1}
    {
        frag_cast zc; zc.f = vzero;
        #pragma unroll
        for (int kt = 0; kt < 4; ++kt) bf[kt] = zc.h;   // h_{-1} = 0
    }
    float c0 = 0.f, c1 = 0.f;
    float* hsp = hs + jj;

#define LSTM_STEP(STEP_T, BUF, XF)                                            \
{                                                                             \
    /* ---- phase A: 32 MFMAs, 8 chains of depth 4 (kt-outer) ---- */         \
    f32x4 cd[8];                                                              \
    _Pragma("unroll")                                                         \
    for (int rt = 0; rt < 8; ++rt)                                            \
        cd[rt] = __builtin_amdgcn_mfma_f32_16x16x32_f16(aw[rt][0], bf[0],     \
                                                        vzero, 0, 0, 0);      \
    _Pragma("unroll")                                                         \
    for (int kt = 1; kt < 4; ++kt) {                                          \
        _Pragma("unroll")                                                     \
        for (int rt = 0; rt < 8; ++rt)                                        \
            cd[rt] = __builtin_amdgcn_mfma_f32_16x16x32_f16(aw[rt][kt],       \
                         bf[kt], cd[rt], 0, 0, 0);                            \
    }                                                                         \
    /* lane (q,n) writes rows j=16n+4q..+3 of gate w (all cols identical) */  \
    _Pragma("unroll")                                                         \
    for (int rt = 0; rt < 8; ++rt)                                            \
        if (n == rt) *(f32x4*)&gl[BUF][w][16 * rt + 4 * q] = cd[rt];          \
    LDS_BARRIER();                                                            \
    /* ---- phase B: all 4 waves redundantly, lane owns j = jj, jj+1 ---- */  \
    float2 a0 = *(const float2*)&gl[BUF][0][jj];                              \
    float2 a1 = *(const float2*)&gl[BUF][1][jj];                              \
    float2 a2 = *(const float2*)&gl[BUF][2][jj];                              \
    float2 a3 = *(const float2*)&gl[BUF][3][jj];                              \
    float gi0 = a0.x + XF[0].x, gi1 = a0.y + XF[0].y;                         \
    float gf0 = a1.x + XF[1].x, gf1 = a1.y + XF[1].y;                         \
    float gg0 = a2.x + XF[2].x, gg1 = a2.y + XF[2].y;                         \
    float go0 = a3.x + XF[3].x, go1 = a3.y + XF[3].y;                         \
    gi0 = 1.f / (1.f + __expf(-gi0));  gi1 = 1.f / (1.f + __expf(-gi1));      \
    gf0 = 1.f / (1.f + __expf(-gf0));  gf1 = 1.f / (1.f + __expf(-gf1));      \
    gg0 = 1.f - 2.f / (1.f + __expf(2.f * gg0));                              \
    gg1 = 1.f - 2.f / (1.f + __expf(2.f * gg1));                              \
    go0 = 1.f / (1.f + __expf(-go0));  go1 = 1.f / (1.f + __expf(-go1));      \
    c0 = gf0 * c0 + gi0 * gg0;                                                \
    c1 = gf1 * c1 + gi1 * gg1;                                                \
    float th0 = 1.f - 2.f / (1.f + __expf(2.f * c0));                         \
    float th1 = 1.f - 2.f / (1.f + __expf(2.f * c1));                         \
    float h0 = go0 * th0, h1 = go1 * th1;                                     \
    int hpk;                                                                  \
    { union { _Float16 hx[2]; int i32; } pk;                                  \
      pk.hx[0] = (_Float16)h0; pk.hx[1] = (_Float16)h1; hpk = pk.i32; }       \
    /* rebuild B-frags wave-locally: frag kt dword d <- lane 16kt+4q+d */     \
    _Pragma("unroll")                                                         \
    for (int kt = 0; kt < 4; ++kt) {                                          \
        int u0 = __builtin_amdgcn_ds_bpermute(4 * (16 * kt + 4 * q + 0), hpk);\
        int u1 = __builtin_amdgcn_ds_bpermute(4 * (16 * kt + 4 * q + 1), hpk);\
        int u2 = __builtin_amdgcn_ds_bpermute(4 * (16 * kt + 4 * q + 2), hpk);\
        int u3 = __builtin_amdgcn_ds_bpermute(4 * (16 * kt + 4 * q + 3), hpk);\
        union { int u[4]; f16x8 h; } bu;                                      \
        bu.u[0] = u0; bu.u[1] = u1; bu.u[2] = u2; bu.u[3] = u3;               \
        bf[kt] = bu.h;                                                        \
    }                                                                         \
    if (q == w) *(float2*)(hsp + (size_t)(STEP_T) * FDIM) = make_float2(h0, h1); \
    { int pid = (STEP_T) + 2; if (pid >= T) pid = T - 1;                      \
      const float* pp = pxl + (size_t)pid * G4H;                              \
      _Pragma("unroll")                                                       \
      for (int g = 0; g < 4; ++g) XF[g] = *(const float2*)(pp + g * FDIM); }  \
}

    for (int step = 0; step + 1 < T; step += 2) {
        LSTM_STEP(step, 0, xfA);
        LSTM_STEP(step + 1, 1, xfB);
    }
    if (T & 1) { LSTM_STEP(T - 1, 0, xfA); }
#undef LSTM_STEP
}

// ---------------------------------------------------------------------------
// out[M x 12] = hs[M x 128] @ w_fc^T + b_fc
// ---------------------------------------------------------------------------
__global__ __launch_bounds__(256) void fc_kernel(const float* __restrict__ hs,
                                                 const float* __restrict__ wfc,
                                                 const float* __restrict__ bfc,
                                                 float* __restrict__ out, int M) {
    __shared__ float wl[12 * FDIM];
    __shared__ float bl[12];
    const int tid = threadIdx.x;
    for (int i = tid; i < 12 * FDIM / 4; i += 256)
        ((float4*)wl)[i] = ((const float4*)wfc)[i];
    if (tid < 12) bl[tid] = bfc[tid];
    __syncthreads();

    int i = blockIdx.x * 256 + tid;
    if (i >= M) return;
    const float* hrow = hs + (size_t)i * FDIM;
    float acc[12];
    #pragma unroll
    for (int t = 0; t < 12; ++t) acc[t] = bl[t];
    for (int k = 0; k < FDIM; k += 4) {
        float4 h4 = *(const float4*)(hrow + k);
        #pragma unroll
        for (int t = 0; t < 12; ++t) {
            acc[t] += h4.x * wl[t * FDIM + k] + h4.y * wl[t * FDIM + k + 1]
                    + h4.z * wl[t * FDIM + k + 2] + h4.w * wl[t * FDIM + k + 3];
        }
    }
    #pragma unroll
    for (int t = 0; t < 12; ++t) out[(size_t)i * 12 + t] = acc[t];
}

// ---------------------------------------------------------------------------
extern "C" void kernel_launch(void* const* d_in, const int* in_sizes, int n_in,
                              void* d_out, int out_size, void* d_ws, size_t ws_size,
                              hipStream_t stream) {
    const float* x    = (const float*)d_in[0];
    const int*   ei   = (const int*)  d_in[1];
    const float* W1   = (const float*)d_in[2];
    const float* b1   = (const float*)d_in[3];
    const float* W2   = (const float*)d_in[4];
    const float* b2   = (const float*)d_in[5];
    const float* w_ih = (const float*)d_in[6];
    const float* w_hh = (const float*)d_in[7];
    const float* b_ih = (const float*)d_in[8];
    const float* b_hh = (const float*)d_in[9];
    const float* w_fc = (const float*)d_in[10];
    const float* b_fc = (const float*)d_in[11];

    const int N = in_sizes[0] / FDIM;     // 20000
    const int E = in_sizes[1] / 2;        // 1280000

    float* ws   = (float*)d_ws;
    int*   deg  = (int*)ws;                       // 20480 ints
    float* dinv = ws + 20480;                     // 20480 floats
    float* whp  = ws + 40960;                     // 32768 dwords (packed fragments)
    int*   rs   = (int*)(ws + 73728);             // 20992 ints (N+1 used)
    int*   cur  = (int*)(ws + 94720);             // 20480 ints
    int*   csr  = (int*)(ws + 115200);            // E ints
    float* hB   = ws + 115200 + 1280000;          // N*128
    float* big  = hB + (size_t)N * FDIM;          // xg region (N*512), aliases y/hA
    float* y    = big;                            // N*128 (dead before xg written)
    float* hA   = big + (size_t)N * FDIM;         // h1   (dead before xg written)
    float* xg   = big;                            // N*512 ([step][gate*128+j])
    float* hs   = big + (size_t)N * G4H;          // N*128

    hipMemsetAsync(deg, 0, (size_t)N * sizeof(int), stream);
    deg_kernel<<<(E + 255) / 256, 256, 0, stream>>>(ei, deg, E);
    dinv_kernel<<<(N + 255) / 256, 256, 0, stream>>>(deg, dinv, N);
    scan_kernel<<<1, 1024, 0, stream>>>(deg, rs, cur, N, E);
    scatter_kernel<<<(E + 255) / 256, 256, 0, stream>>>(ei, cur, csr, E);
    pack_whh<<<(32768 + 255) / 256, 256, 0, stream>>>(w_hh, whp, 32768);

    const int gblocks = (N + 31) / 32;
    const int ablocks = (N + 3) / 4;
    // layer 1
    gemm_nn<<<gblocks, 256, 0, stream>>>(x, W1, y, N);
    agg_gather<<<ablocks, 256, 0, stream>>>(y, rs, csr, dinv, b1, hA, N);
    // layer 2
    gemm_nn<<<gblocks, 256, 0, stream>>>(hA, W2, y, N);
    agg_gather<<<ablocks, 256, 0, stream>>>(y, rs, csr, dinv, b2, hB, N);
    // LSTM input projection
    gemm_nt_xg<<<dim3(gblocks, 4), 256, 0, stream>>>(hB, w_ih, b_ih, b_hh, xg, N);
    // sequential LSTM (single CU — the critical path), v16: 4 waves
    lstm_kernel<<<1, 256, 0, stream>>>(xg, whp, hs, N);
    // final projection
    fc_kernel<<<(N + 255) / 256, 256, 0, stream>>>(hs, w_fc, b_fc, (float*)d_out, N);
}

// Round 2
// 16328.453 us; speedup vs baseline: 1.2966x; 1.2966x over previous
//
#include <hip/hip_runtime.h>
#include <hip/hip_bf16.h>
#include <hip/hip_fp16.h>

// Problem constants (fixed by the reference)
#define FDIM 128      // F_IN == H == 128
#define G4H  512      // 4*H

typedef float f32x4 __attribute__((ext_vector_type(4)));
typedef _Float16 f16x8 __attribute__((ext_vector_type(8)));

union frag_cast { f32x4 f; f16x8 h; };

// LDS-only barrier: does NOT drain vmcnt (global ops stay in flight).
#define LDS_BARRIER() asm volatile("s_waitcnt lgkmcnt(0)\n\ts_barrier" ::: "memory")

#define AS1 __attribute__((address_space(1)))
#define AS3 __attribute__((address_space(3)))
// Async global->LDS, 16B/lane: LDS dst = uniform base + lane*16.
__device__ __forceinline__ void load_lds16(const float* g, float* l) {
    __builtin_amdgcn_global_load_lds((const AS1 unsigned int*)g,
                                     (AS3 unsigned int*)l, 16, 0, 0);
}

// ---------------------------------------------------------------------------
// degree / normalization
// ---------------------------------------------------------------------------
__global__ void deg_kernel(const int* __restrict__ ei, int* __restrict__ deg, int E) {
    int e = blockIdx.x * 256 + threadIdx.x;
    if (e < E) atomicAdd(&deg[ei[E + e]], 1);
}

__global__ void dinv_kernel(const int* __restrict__ deg, float* __restrict__ dinv, int N) {
    int n = blockIdx.x * 256 + threadIdx.x;
    if (n < N) dinv[n] = rsqrtf((float)(deg[n] + 1));   // +1 self-loop
}

// ---------------------------------------------------------------------------
// CSR build: exclusive scan of deg (1024 thr x 20 nodes), then edge scatter.
// ---------------------------------------------------------------------------
__global__ __launch_bounds__(1024) void scan_kernel(const int* __restrict__ deg,
                                                    int* __restrict__ rs,
                                                    int* __restrict__ cursor,
                                                    int N, int E) {
    __shared__ int buf[2][1024];
    const int t = threadIdx.x;
    const int base = t * 20;
    int loc[20]; int s = 0;
    #pragma unroll
    for (int i = 0; i < 20; ++i) {
        int n = base + i;
        int d = (n < N) ? deg[n] : 0;
        loc[i] = s; s += d;
    }
    buf[0][t] = s; __syncthreads();
    int pb = 0;
    for (int off = 1; off < 1024; off <<= 1) {
        int v = buf[pb][t] + ((t >= off) ? buf[pb][t - off] : 0);
        buf[pb ^ 1][t] = v; pb ^= 1; __syncthreads();
    }
    int pre = (t > 0) ? buf[pb][t - 1] : 0;   // exclusive prefix
    #pragma unroll
    for (int i = 0; i < 20; ++i) {
        int n = base + i;
        if (n < N) { int v = pre + loc[i]; rs[n] = v; cursor[n] = v; }
    }
    if (t == 0) rs[N] = E;
}

__global__ void scatter_kernel(const int* __restrict__ ei, int* __restrict__ cursor,
                               int* __restrict__ csr_src, int E) {
    int e = blockIdx.x * 256 + threadIdx.x;
    if (e >= E) return;
    int s = ei[e], d = ei[E + e];
    int pos = atomicAdd(&cursor[d], 1);
    csr_src[pos] = s;
}

// ---------------------------------------------------------------------------
// C[M x 128] = A[M x 128] @ B[128 x 128]   (B is K-major: B[k*128 + j])
// ---------------------------------------------------------------------------
__global__ __launch_bounds__(256) void gemm_nn(const float* __restrict__ A,
                                               const float* __restrict__ B,
                                               float* __restrict__ C, int M) {
    __shared__ float Bl[64 * 132];
    __shared__ float Al[32][FDIM];
    const int tid = threadIdx.x;
    const int row0 = blockIdx.x * 32;

    for (int i = tid * 4; i < 32 * FDIM; i += 1024) {
        int r = i >> 7, k = i & 127;
        int row = row0 + r;
        float4 v = make_float4(0.f, 0.f, 0.f, 0.f);
        if (row < M) v = *(const float4*)(A + (size_t)row * FDIM + k);
        *(float4*)&Al[r][k] = v;
    }

    const int jg = tid & 31, rg = tid >> 5;
    float acc[4][4] = {};

    for (int kh = 0; kh < 2; ++kh) {
        __syncthreads();
        for (int i = tid * 4; i < 64 * FDIM; i += 1024) {
            int k = i >> 7, j = i & 127;
            *(float4*)&Bl[k * 132 + j] = *(const float4*)(B + (size_t)(kh * 64 + k) * FDIM + j);
        }
        __syncthreads();
        #pragma unroll 4
        for (int k = 0; k < 64; ++k) {
            float4 b4 = *(const float4*)&Bl[k * 132 + jg * 4];
            #pragma unroll
            for (int rr = 0; rr < 4; ++rr) {
                float a = Al[rg * 4 + rr][kh * 64 + k];
                acc[rr][0] += a * b4.x; acc[rr][1] += a * b4.y;
                acc[rr][2] += a * b4.z; acc[rr][3] += a * b4.w;
            }
        }
    }
    #pragma unroll
    for (int rr = 0; rr < 4; ++rr) {
        int row = row0 + rg * 4 + rr;
        if (row < M) {
            float4 v = make_float4(acc[rr][0], acc[rr][1], acc[rr][2], acc[rr][3]);
            *(float4*)(C + (size_t)row * FDIM + jg * 4) = v;
        }
    }
}

// ---------------------------------------------------------------------------
// xg[M x 512] = A[M x 128] @ B^T  (+ b_ih + b_hh), B is [512 x 128] row-major.
// Output layout [step][gate*128 + j].
// ---------------------------------------------------------------------------
__global__ __launch_bounds__(256) void gemm_nt_xg(const float* __restrict__ A,
                                                  const float* __restrict__ B,
                                                  const float* __restrict__ bih,
                                                  const float* __restrict__ bhh,
                                                  float* __restrict__ C, int M) {
    __shared__ float Bl[64 * 132];
    __shared__ float Al[32][FDIM];
    const int tid = threadIdx.x;
    const int row0 = blockIdx.x * 32;
    const int chunk = blockIdx.y;

    for (int i = tid * 4; i < 32 * FDIM; i += 1024) {
        int r = i >> 7, k = i & 127;
        int row = row0 + r;
        float4 v = make_float4(0.f, 0.f, 0.f, 0.f);
        if (row < M) v = *(const float4*)(A + (size_t)row * FDIM + k);
        *(float4*)&Al[r][k] = v;
    }

    const int jg = tid & 31, rg = tid >> 5;
    float acc[4][4] = {};

    for (int kh = 0; kh < 2; ++kh) {
        __syncthreads();
        for (int i = tid * 4; i < 128 * 64; i += 1024) {
            int g = i >> 6, kl = i & 63;
            float4 v = *(const float4*)(B + (size_t)(chunk * 128 + g) * FDIM + kh * 64 + kl);
            Bl[(kl + 0) * 132 + g] = v.x;
            Bl[(kl + 1) * 132 + g] = v.y;
            Bl[(kl + 2) * 132 + g] = v.z;
            Bl[(kl + 3) * 132 + g] = v.w;
        }
        __syncthreads();
        #pragma unroll 4
        for (int k = 0; k < 64; ++k) {
            float4 b4 = *(const float4*)&Bl[k * 132 + jg * 4];
            #pragma unroll
            for (int rr = 0; rr < 4; ++rr) {
                float a = Al[rg * 4 + rr][kh * 64 + k];
                acc[rr][0] += a * b4.x; acc[rr][1] += a * b4.y;
                acc[rr][2] += a * b4.z; acc[rr][3] += a * b4.w;
            }
        }
    }
    const int col0 = chunk * 128 + jg * 4;
    float4 bsum = make_float4(bih[col0 + 0] + bhh[col0 + 0],
                              bih[col0 + 1] + bhh[col0 + 1],
                              bih[col0 + 2] + bhh[col0 + 2],
                              bih[col0 + 3] + bhh[col0 + 3]);
    #pragma unroll
    for (int rr = 0; rr < 4; ++rr) {
        int row = row0 + rg * 4 + rr;
        if (row < M) {
            float4 v = make_float4(acc[rr][0] + bsum.x, acc[rr][1] + bsum.y,
                                   acc[rr][2] + bsum.z, acc[rr][3] + bsum.w);
            *(float4*)(C + (size_t)row * G4H + col0) = v;
        }
    }
}

// ---------------------------------------------------------------------------
// Fused GCN aggregation (CSR gather): one wave per node, registers, one write.
// ---------------------------------------------------------------------------
__global__ __launch_bounds__(256) void agg_gather(const float* __restrict__ y,
                                                  const int* __restrict__ rs,
                                                  const int* __restrict__ csr_src,
                                                  const float* __restrict__ dinv,
                                                  const float* __restrict__ bias,
                                                  float* __restrict__ o, int N) {
    const int node = blockIdx.x * 4 + (threadIdx.x >> 6);
    if (node >= N) return;
    const int lane = threadIdx.x & 63;
    const int beg = rs[node], end = rs[node + 1];
    const float dn = dinv[node];

    float2 yv = *(const float2*)(y + (size_t)node * FDIM + lane * 2);
    float2 acc = make_float2(yv.x * dn * dn, yv.y * dn * dn);

    for (int base = beg; base < end; base += 64) {
        int cnt = end - base; if (cnt > 64) cnt = 64;
        int msrc = 0; float mnrm = 0.f;
        if (lane < cnt) {
            msrc = csr_src[base + lane];
            mnrm = dinv[msrc] * dn;
        }
        for (int j = 0; j < cnt; ++j) {
            int s = __shfl(msrc, j);
            float nr = __shfl(mnrm, j);
            float2 v = *(const float2*)(y + (size_t)s * FDIM + lane * 2);
            acc.x += v.x * nr;
            acc.y += v.y * nr;
        }
    }
    float2 b = *(const float2*)(bias + lane * 2);
    acc.x = fmaxf(acc.x + b.x, 0.f);
    acc.y = fmaxf(acc.y + b.y, 0.f);
    *(float2*)(o + (size_t)node * FDIM + lane * 2) = acc;
}

// ---------------------------------------------------------------------------
// Prepack w_hh [512 x 128] fp32 into fp16 MFMA A-fragments.
// dword idx = (((w8*4+rt)*4+kt)*64 + lane)*4 + d
//   row r = 64*w8 + 16*rt + (lane&15); k = 32*kt + 8*(lane>>4) + {2d, 2d+1}.
// v17 LSTM indexes frag (wave w, gate g, kt) as w8 = 2g + (w>>2), rt = w&3,
// which yields rows r = 128*g + 16*w + m  (wave w owns 16 rows of ALL gates).
// ---------------------------------------------------------------------------
__global__ void pack_whh(const float* __restrict__ whh, float* __restrict__ whp, int n) {
    int i = blockIdx.x * 256 + threadIdx.x;   // n = 32768 dwords
    if (i >= n) return;
    int d = i & 3, fi = i >> 2;
    int lane = fi & 63, kt = (fi >> 6) & 3, rt = (fi >> 8) & 3, w = fi >> 10;
    int m = lane & 15, q = lane >> 4;
    int r = 64 * w + 16 * rt + m;
    int k = 32 * kt + 8 * q + 2 * d;
    __half lo = __float2half(whh[r * FDIM + k]);
    __half hi = __float2half(whh[r * FDIM + k + 1]);
    unsigned u = ((unsigned)__half_as_ushort(hi) << 16) | (unsigned)__half_as_ushort(lo);
    whp[i] = __uint_as_float(u);
}

// ---------------------------------------------------------------------------
// LSTM v17: 8 waves (2/SIMD, keeps MFMA||VALU co-issue), row-partitioned
// gates, LANE-LOCAL phase B, ONE barrier/step.
//
// Wave w owns rows [16w, 16w+16) of ALL FOUR gates (4 MFMA chains x 4 kt =
// 16 MFMAs/wave, 128 total — same MFMA work as v9). Because the MFMA C/D
// layout puts row 4q+d in reg d of lanes with lane>>4==q (all 16 columns
// identical for a broadcast-B GEMV), lane (q,n) already holds i,f,g,o for
// hidden unit j = 16w + 4q + (n&3): phase B needs NO gates LDS round-trip,
// no second barrier, and runs 1 LSTM cell per lane (the 16-column redundancy
// pays for the n&3 split). Per step:
//   read bf from hl[step&1] (4x ds_read_b128 broadcast)  -> 16 MFMAs
//   lane-local: extract reg n&3, + xg from LDS ring, activations, c update
//   lanes n<4 write h to hl[step&1 ^ 1] (fp16) and hs (fp32)
//   wave 2: stream xg[step+3] into 4-slot ring, vmcnt(4)
//   ONE LDS barrier (double-buffered hl kills the WAR barrier)
// v9 had 2 barriers + gates round-trip + phase B on 2 waves: 1587 cyc/step.
// v16 (4 waves, bpermute) lost MFMA||VALU co-issue: 2500 cyc/step. v17 keeps
// v9's wave config and removes one full round-trip: model ~650-1000 cyc/step.
// ---------------------------------------------------------------------------
__global__ void __launch_bounds__(512, 2)
lstm_kernel(const float* __restrict__ xg, const float* __restrict__ whp,
            float* __restrict__ hs, int T) {
    __shared__ __align__(16) __half hl[2][FDIM];     // double-buffered h (fp16)
    __shared__ __align__(16) float xr[4][G4H];       // xg ring, slot = step & 3
    const int t    = threadIdx.x;
    const int w    = t >> 6;        // wave 0..7: rows [16w, 16w+16) of all gates
    const int lane = t & 63;
    const int q    = lane >> 4;     // C row-quad / B k-quad
    const int n    = lane & 15;     // C column (redundant) -> cell selector n&3
    const int d    = n & 3;         // which of the 4 rows in reg file this lane owns
    const int j    = 16 * w + 4 * q + d;   // this lane's hidden unit

    // ---- A-fragments: af[g][kt] covers rows 128g + 16w + m, k = 32kt+8q+e
    f16x8 af[4][4];
    {
        const f32x4* wp4 = (const f32x4*)whp;
        #pragma unroll
        for (int g = 0; g < 4; ++g) {
            const int w8 = 2 * g + (w >> 2);
            const int rt = w & 3;
            #pragma unroll
            for (int kt = 0; kt < 4; ++kt) {
                frag_cast fc;
                fc.f = wp4[((w8 * 4 + rt) * 4 + kt) * 64 + lane];
                f16x8 tmp = fc.h;
                asm volatile("" : "=a"(af[g][kt]) : "0"(tmp));  // pin to AGPR class
            }
        }
    }

    const f32x4 vzero = {0.f, 0.f, 0.f, 0.f};

    // h_{-1} = 0: zero hl[0] (128 halves = 64 dwords)
    if (t < 64) ((unsigned*)hl)[t] = 0u;
    // Prime the xg ring: slots 0..2 (6 outstanding vm ops on wave 2).
    if (w == 2) {
        #pragma unroll
        for (int i = 0; i < 3; ++i) {
            const float* g0 = xg + (size_t)i * G4H + lane * 4;
            load_lds16(g0,       &xr[i][0]);
            load_lds16(g0 + 256, &xr[i][256]);
        }
    }
    float c = 0.f;
    __syncthreads();   // drains vmcnt: slots 0..2 landed, hl[0] zeroed

    for (int step = 0; step < T; ++step) {
        const int buf = step & 1;

        // ---- B-fragments: h[32kt+8q .. +8) broadcast (same-addr per q-group)
        f16x8 bfr[4];
        #pragma unroll
        for (int kt = 0; kt < 4; ++kt) {
            frag_cast fc;
            fc.f = *(const f32x4*)((const char*)hl[buf] + kt * 64 + q * 16);
            bfr[kt] = fc.h;
        }

        // ---- 16 MFMAs: 4 gate-chains x depth 4
        f32x4 cd[4];
        #pragma unroll
        for (int g = 0; g < 4; ++g)
            cd[g] = __builtin_amdgcn_mfma_f32_16x16x32_f16(af[g][0], bfr[0], vzero, 0, 0, 0);
        #pragma unroll
        for (int kt = 1; kt < 4; ++kt) {
            #pragma unroll
            for (int g = 0; g < 4; ++g)
                cd[g] = __builtin_amdgcn_mfma_f32_16x16x32_f16(af[g][kt], bfr[kt], cd[g], 0, 0, 0);
        }

        // ---- phase B, lane-local: reg d of cd[g] is gate g, row j
        float ga[4];
        #pragma unroll
        for (int g = 0; g < 4; ++g) {
            f32x4 v = cd[g];
            ga[g] = (d == 0) ? v.x : (d == 1) ? v.y : (d == 2) ? v.z : v.w;
        }
        const float* xb = &xr[step & 3][j];
        float gi = ga[0] + xb[0];
        float gf = ga[1] + xb[128];
        float gg = ga[2] + xb[256];
        float go = ga[3] + xb[384];
        gi = 1.f / (1.f + __expf(-gi));
        gf = 1.f / (1.f + __expf(-gf));
        gg = 1.f - 2.f / (1.f + __expf(2.f * gg));
        go = 1.f / (1.f + __expf(-go));
        c = gf * c + gi * gg;
        float th = 1.f - 2.f / (1.f + __expf(2.f * c));
        float h = go * th;
        if (n < 4) {                         // one replica per (q,d) writes
            hl[buf ^ 1][j] = __float2half(h);
            hs[(size_t)step * FDIM + j] = h; // store: never waited on in-loop
        }

        // ---- wave 2: stream xg[step+3] into ring slot (step+3)&3 ----
        if (w == 2) {
            int pid = step + 3; if (pid >= T) pid = T - 1;
            const float* g0 = xg + (size_t)pid * G4H + lane * 4;
            load_lds16(g0,       &xr[pid & 3][0]);
            load_lds16(g0 + 256, &xr[pid & 3][256]);
            // force slot step+1 landed (consumed right after this barrier)
            asm volatile("s_waitcnt vmcnt(4)" ::: "memory");
        }
        LDS_BARRIER();   // the ONLY barrier: h visible, ring slot visible
    }
}

// ---------------------------------------------------------------------------
// out[M x 12] = hs[M x 128] @ w_fc^T + b_fc
// ---------------------------------------------------------------------------
__global__ __launch_bounds__(256) void fc_kernel(const float* __restrict__ hs,
                                                 const float* __restrict__ wfc,
                                                 const float* __restrict__ bfc,
                                                 float* __restrict__ out, int M) {
    __shared__ float wl[12 * FDIM];
    __shared__ float bl[12];
    const int tid = threadIdx.x;
    for (int i = tid; i < 12 * FDIM / 4; i += 256)
        ((float4*)wl)[i] = ((const float4*)wfc)[i];
    if (tid < 12) bl[tid] = bfc[tid];
    __syncthreads();

    int i = blockIdx.x * 256 + tid;
    if (i >= M) return;
    const float* hrow = hs + (size_t)i * FDIM;
    float acc[12];
    #pragma unroll
    for (int t = 0; t < 12; ++t) acc[t] = bl[t];
    for (int k = 0; k < FDIM; k += 4) {
        float4 h4 = *(const float4*)(hrow + k);
        #pragma unroll
        for (int t = 0; t < 12; ++t) {
            acc[t] += h4.x * wl[t * FDIM + k] + h4.y * wl[t * FDIM + k + 1]
                    + h4.z * wl[t * FDIM + k + 2] + h4.w * wl[t * FDIM + k + 3];
        }
    }
    #pragma unroll
    for (int t = 0; t < 12; ++t) out[(size_t)i * 12 + t] = acc[t];
}

// ---------------------------------------------------------------------------
extern "C" void kernel_launch(void* const* d_in, const int* in_sizes, int n_in,
                              void* d_out, int out_size, void* d_ws, size_t ws_size,
                              hipStream_t stream) {
    const float* x    = (const float*)d_in[0];
    const int*   ei   = (const int*)  d_in[1];
    const float* W1   = (const float*)d_in[2];
    const float* b1   = (const float*)d_in[3];
    const float* W2   = (const float*)d_in[4];
    const float* b2   = (const float*)d_in[5];
    const float* w_ih = (const float*)d_in[6];
    const float* w_hh = (const float*)d_in[7];
    const float* b_ih = (const float*)d_in[8];
    const float* b_hh = (const float*)d_in[9];
    const float* w_fc = (const float*)d_in[10];
    const float* b_fc = (const float*)d_in[11];

    const int N = in_sizes[0] / FDIM;     // 20000
    const int E = in_sizes[1] / 2;        // 1280000

    float* ws   = (float*)d_ws;
    int*   deg  = (int*)ws;                       // 20480 ints
    float* dinv = ws + 20480;                     // 20480 floats
    float* whp  = ws + 40960;                     // 32768 dwords (packed fragments)
    int*   rs   = (int*)(ws + 73728);             // 20992 ints (N+1 used)
    int*   cur  = (int*)(ws + 94720);             // 20480 ints
    int*   csr  = (int*)(ws + 115200);            // E ints
    float* hB   = ws + 115200 + 1280000;          // N*128
    float* big  = hB + (size_t)N * FDIM;          // xg region (N*512), aliases y/hA
    float* y    = big;                            // N*128 (dead before xg written)
    float* hA   = big + (size_t)N * FDIM;         // h1   (dead before xg written)
    float* xg   = big;                            // N*512 ([step][gate*128+j])
    float* hs   = big + (size_t)N * G4H;          // N*128

    hipMemsetAsync(deg, 0, (size_t)N * sizeof(int), stream);
    deg_kernel<<<(E + 255) / 256, 256, 0, stream>>>(ei, deg, E);
    dinv_kernel<<<(N + 255) / 256, 256, 0, stream>>>(deg, dinv, N);
    scan_kernel<<<1, 1024, 0, stream>>>(deg, rs, cur, N, E);
    scatter_kernel<<<(E + 255) / 256, 256, 0, stream>>>(ei, cur, csr, E);
    pack_whh<<<(32768 + 255) / 256, 256, 0, stream>>>(w_hh, whp, 32768);

    const int gblocks = (N + 31) / 32;
    const int ablocks = (N + 3) / 4;
    // layer 1
    gemm_nn<<<gblocks, 256, 0, stream>>>(x, W1, y, N);
    agg_gather<<<ablocks, 256, 0, stream>>>(y, rs, csr, dinv, b1, hA, N);
    // layer 2
    gemm_nn<<<gblocks, 256, 0, stream>>>(hA, W2, y, N);
    agg_gather<<<ablocks, 256, 0, stream>>>(y, rs, csr, dinv, b2, hB, N);
    // LSTM input projection
    gemm_nt_xg<<<dim3(gblocks, 4), 256, 0, stream>>>(hB, w_ih, b_ih, b_hh, xg, N);
    // sequential LSTM (single CU — the critical path), v17: 8 waves, 1 barrier
    lstm_kernel<<<1, 512, 0, stream>>>(xg, whp, hs, N);
    // final projection
    fc_kernel<<<(N + 255) / 256, 256, 0, stream>>>(hs, w_fc, b_fc, (float*)d_out, N);
}

// Round 3
// 10455.037 us; speedup vs baseline: 2.0249x; 1.5618x over previous
//
#include <hip/hip_runtime.h>
#include <hip/hip_bf16.h>
#include <hip/hip_fp16.h>

// Problem constants (fixed by the reference)
#define FDIM 128      // F_IN == H == 128
#define G4H  512      // 4*H

typedef float f32x4 __attribute__((ext_vector_type(4)));
typedef _Float16 f16x8 __attribute__((ext_vector_type(8)));

union frag_cast { f32x4 f; f16x8 h; };

// LDS-only barrier: does NOT drain vmcnt (global ops stay in flight).
#define LDS_BARRIER() asm volatile("s_waitcnt lgkmcnt(0)\n\ts_barrier" ::: "memory")

#define AS1 __attribute__((address_space(1)))
#define AS3 __attribute__((address_space(3)))
// Async global->LDS, 16B/lane: LDS dst = uniform base + lane*16. (unused by v18 LSTM)
__device__ __forceinline__ void load_lds16(const float* g, float* l) {
    __builtin_amdgcn_global_load_lds((const AS1 unsigned int*)g,
                                     (AS3 unsigned int*)l, 16, 0, 0);
}

// ---------------------------------------------------------------------------
// degree / normalization
// ---------------------------------------------------------------------------
__global__ void deg_kernel(const int* __restrict__ ei, int* __restrict__ deg, int E) {
    int e = blockIdx.x * 256 + threadIdx.x;
    if (e < E) atomicAdd(&deg[ei[E + e]], 1);
}

__global__ void dinv_kernel(const int* __restrict__ deg, float* __restrict__ dinv, int N) {
    int n = blockIdx.x * 256 + threadIdx.x;
    if (n < N) dinv[n] = rsqrtf((float)(deg[n] + 1));   // +1 self-loop
}

// ---------------------------------------------------------------------------
// CSR build: exclusive scan of deg (1024 thr x 20 nodes), then edge scatter.
// ---------------------------------------------------------------------------
__global__ __launch_bounds__(1024) void scan_kernel(const int* __restrict__ deg,
                                                    int* __restrict__ rs,
                                                    int* __restrict__ cursor,
                                                    int N, int E) {
    __shared__ int buf[2][1024];
    const int t = threadIdx.x;
    const int base = t * 20;
    int loc[20]; int s = 0;
    #pragma unroll
    for (int i = 0; i < 20; ++i) {
        int n = base + i;
        int d = (n < N) ? deg[n] : 0;
        loc[i] = s; s += d;
    }
    buf[0][t] = s; __syncthreads();
    int pb = 0;
    for (int off = 1; off < 1024; off <<= 1) {
        int v = buf[pb][t] + ((t >= off) ? buf[pb][t - off] : 0);
        buf[pb ^ 1][t] = v; pb ^= 1; __syncthreads();
    }
    int pre = (t > 0) ? buf[pb][t - 1] : 0;   // exclusive prefix
    #pragma unroll
    for (int i = 0; i < 20; ++i) {
        int n = base + i;
        if (n < N) { int v = pre + loc[i]; rs[n] = v; cursor[n] = v; }
    }
    if (t == 0) rs[N] = E;
}

__global__ void scatter_kernel(const int* __restrict__ ei, int* __restrict__ cursor,
                               int* __restrict__ csr_src, int E) {
    int e = blockIdx.x * 256 + threadIdx.x;
    if (e >= E) return;
    int s = ei[e], d = ei[E + e];
    int pos = atomicAdd(&cursor[d], 1);
    csr_src[pos] = s;
}

// ---------------------------------------------------------------------------
// C[M x 128] = A[M x 128] @ B[128 x 128]   (B is K-major: B[k*128 + j])
// ---------------------------------------------------------------------------
__global__ __launch_bounds__(256) void gemm_nn(const float* __restrict__ A,
                                               const float* __restrict__ B,
                                               float* __restrict__ C, int M) {
    __shared__ float Bl[64 * 132];
    __shared__ float Al[32][FDIM];
    const int tid = threadIdx.x;
    const int row0 = blockIdx.x * 32;

    for (int i = tid * 4; i < 32 * FDIM; i += 1024) {
        int r = i >> 7, k = i & 127;
        int row = row0 + r;
        float4 v = make_float4(0.f, 0.f, 0.f, 0.f);
        if (row < M) v = *(const float4*)(A + (size_t)row * FDIM + k);
        *(float4*)&Al[r][k] = v;
    }

    const int jg = tid & 31, rg = tid >> 5;
    float acc[4][4] = {};

    for (int kh = 0; kh < 2; ++kh) {
        __syncthreads();
        for (int i = tid * 4; i < 64 * FDIM; i += 1024) {
            int k = i >> 7, j = i & 127;
            *(float4*)&Bl[k * 132 + j] = *(const float4*)(B + (size_t)(kh * 64 + k) * FDIM + j);
        }
        __syncthreads();
        #pragma unroll 4
        for (int k = 0; k < 64; ++k) {
            float4 b4 = *(const float4*)&Bl[k * 132 + jg * 4];
            #pragma unroll
            for (int rr = 0; rr < 4; ++rr) {
                float a = Al[rg * 4 + rr][kh * 64 + k];
                acc[rr][0] += a * b4.x; acc[rr][1] += a * b4.y;
                acc[rr][2] += a * b4.z; acc[rr][3] += a * b4.w;
            }
        }
    }
    #pragma unroll
    for (int rr = 0; rr < 4; ++rr) {
        int row = row0 + rg * 4 + rr;
        if (row < M) {
            float4 v = make_float4(acc[rr][0], acc[rr][1], acc[rr][2], acc[rr][3]);
            *(float4*)(C + (size_t)row * FDIM + jg * 4) = v;
        }
    }
}

// ---------------------------------------------------------------------------
// xg[M x 512] = A[M x 128] @ B^T  (+ b_ih + b_hh), B is [512 x 128] row-major.
// Output layout [step][gate*128 + j].
// ---------------------------------------------------------------------------
__global__ __launch_bounds__(256) void gemm_nt_xg(const float* __restrict__ A,
                                                  const float* __restrict__ B,
                                                  const float* __restrict__ bih,
                                                  const float* __restrict__ bhh,
                                                  float* __restrict__ C, int M) {
    __shared__ float Bl[64 * 132];
    __shared__ float Al[32][FDIM];
    const int tid = threadIdx.x;
    const int row0 = blockIdx.x * 32;
    const int chunk = blockIdx.y;

    for (int i = tid * 4; i < 32 * FDIM; i += 1024) {
        int r = i >> 7, k = i & 127;
        int row = row0 + r;
        float4 v = make_float4(0.f, 0.f, 0.f, 0.f);
        if (row < M) v = *(const float4*)(A + (size_t)row * FDIM + k);
        *(float4*)&Al[r][k] = v;
    }

    const int jg = tid & 31, rg = tid >> 5;
    float acc[4][4] = {};

    for (int kh = 0; kh < 2; ++kh) {
        __syncthreads();
        for (int i = tid * 4; i < 128 * 64; i += 1024) {
            int g = i >> 6, kl = i & 63;
            float4 v = *(const float4*)(B + (size_t)(chunk * 128 + g) * FDIM + kh * 64 + kl);
            Bl[(kl + 0) * 132 + g] = v.x;
            Bl[(kl + 1) * 132 + g] = v.y;
            Bl[(kl + 2) * 132 + g] = v.z;
            Bl[(kl + 3) * 132 + g] = v.w;
        }
        __syncthreads();
        #pragma unroll 4
        for (int k = 0; k < 64; ++k) {
            float4 b4 = *(const float4*)&Bl[k * 132 + jg * 4];
            #pragma unroll
            for (int rr = 0; rr < 4; ++rr) {
                float a = Al[rg * 4 + rr][kh * 64 + k];
                acc[rr][0] += a * b4.x; acc[rr][1] += a * b4.y;
                acc[rr][2] += a * b4.z; acc[rr][3] += a * b4.w;
            }
        }
    }
    const int col0 = chunk * 128 + jg * 4;
    float4 bsum = make_float4(bih[col0 + 0] + bhh[col0 + 0],
                              bih[col0 + 1] + bhh[col0 + 1],
                              bih[col0 + 2] + bhh[col0 + 2],
                              bih[col0 + 3] + bhh[col0 + 3]);
    #pragma unroll
    for (int rr = 0; rr < 4; ++rr) {
        int row = row0 + rg * 4 + rr;
        if (row < M) {
            float4 v = make_float4(acc[rr][0] + bsum.x, acc[rr][1] + bsum.y,
                                   acc[rr][2] + bsum.z, acc[rr][3] + bsum.w);
            *(float4*)(C + (size_t)row * G4H + col0) = v;
        }
    }
}

// ---------------------------------------------------------------------------
// Fused GCN aggregation (CSR gather): one wave per node, registers, one write.
// ---------------------------------------------------------------------------
__global__ __launch_bounds__(256) void agg_gather(const float* __restrict__ y,
                                                  const int* __restrict__ rs,
                                                  const int* __restrict__ csr_src,
                                                  const float* __restrict__ dinv,
                                                  const float* __restrict__ bias,
                                                  float* __restrict__ o, int N) {
    const int node = blockIdx.x * 4 + (threadIdx.x >> 6);
    if (node >= N) return;
    const int lane = threadIdx.x & 63;
    const int beg = rs[node], end = rs[node + 1];
    const float dn = dinv[node];

    float2 yv = *(const float2*)(y + (size_t)node * FDIM + lane * 2);
    float2 acc = make_float2(yv.x * dn * dn, yv.y * dn * dn);

    for (int base = beg; base < end; base += 64) {
        int cnt = end - base; if (cnt > 64) cnt = 64;
        int msrc = 0; float mnrm = 0.f;
        if (lane < cnt) {
            msrc = csr_src[base + lane];
            mnrm = dinv[msrc] * dn;
        }
        for (int j = 0; j < cnt; ++j) {
            int s = __shfl(msrc, j);
            float nr = __shfl(mnrm, j);
            float2 v = *(const float2*)(y + (size_t)s * FDIM + lane * 2);
            acc.x += v.x * nr;
            acc.y += v.y * nr;
        }
    }
    float2 b = *(const float2*)(bias + lane * 2);
    acc.x = fmaxf(acc.x + b.x, 0.f);
    acc.y = fmaxf(acc.y + b.y, 0.f);
    *(float2*)(o + (size_t)node * FDIM + lane * 2) = acc;
}

// ---------------------------------------------------------------------------
// Prepack w_hh [512 x 128] fp32 into fp16 MFMA **B**-fragments (v18 layout).
// dword idx i: d = i&3; fi = i>>2; lane = fi&63; kt=(fi>>6)&3; g=(fi>>8)&3;
//              tl=(fi>>10)&1; w=fi>>11  (w = wave 0..3).
// B-operand mapping (16x16x32): col = lane&15, k = 8*(lane>>4) + elem.
// Fragment (w,tl,g,kt) supplies B[k][col] = W[row][k] with
//   row = 128*g + 32*w + 16*tl + (lane&15),  k = 32*kt + 8*(lane>>4) + 2d,2d+1.
// So wave w's MFMA (A = h broadcast) yields gate g of cells 32w+16tl+col
// directly in C/D col = lane&15, identical across C rows.
// ---------------------------------------------------------------------------
__global__ void pack_whh(const float* __restrict__ whh, float* __restrict__ whp, int n) {
    int i = blockIdx.x * 256 + threadIdx.x;   // n = 32768 dwords
    if (i >= n) return;
    int d = i & 3, fi = i >> 2;
    int lane = fi & 63, kt = (fi >> 6) & 3, g = (fi >> 8) & 3;
    int tl = (fi >> 10) & 1, w = fi >> 11;
    int m = lane & 15, q = lane >> 4;
    int r = 128 * g + 32 * w + 16 * tl + m;
    int k = 32 * kt + 8 * q + 2 * d;
    __half lo = __float2half(whh[r * FDIM + k]);
    __half hi = __float2half(whh[r * FDIM + k + 1]);
    unsigned u = ((unsigned)__half_as_ushort(hi) << 16) | (unsigned)__half_as_ushort(lo);
    whp[i] = __uint_as_float(u);
}

// ---------------------------------------------------------------------------
// LSTM v18: 4 waves (1/SIMD), A/B-swapped MFMA (A = h broadcast, B = weights),
// lane-local gates with NO extraction, ONE barrier/step, no LDS xg ring.
//
// v17 post-mortem: VALUBusy doubled (act stream on 8 waves, 2/SIMD -> ~380
// issue-cyc/SIMD/step) and extraction cost 12 cndmask + accvgpr reads. Fixes:
//   (1) A/B swap: D[row][col] = sum_k h[k] * W[j(col)][k] is uniform across
//       rows, so lane (q,n) reads gate-for-cell-n from .x of any accumulator
//       -> extraction reduced to ONE cndmask per gate (2-tile select).
//   (2) 4 waves x 32 cells: act instruction count per wave is independent of
//       cells/wave (1 cell/lane), so total VALU/trans issue halves; MFMA
//       becomes 32/wave (2 tiles x 4 gates x 4 kt, 8 indep chains of 4).
//   (3) xg: per-lane global->register prefetch 2 steps ahead (4 scalar loads
//       at fixed offsets); removes the entire LDS ring + in-loop vmcnt dance
//       (~40 DS instrs/step off the LDS pipe).
// Per step: 4x ds_read_b128 (h bcast) -> 32 MFMA -> 4 cndmask -> act (1
// cell/lane, 2x q-redundant) -> ds_write_b16 (q even lanes) + hs store ->
// prefetch -> LDS barrier. Model: ~550-800 cyc/step (v9: 1582, v17: 1918).
// ---------------------------------------------------------------------------
__global__ void __launch_bounds__(256, 1)
lstm_kernel(const float* __restrict__ xg, const float* __restrict__ whp,
            float* __restrict__ hs, int T) {
    __shared__ __align__(16) __half hl[2][FDIM];     // double-buffered h (fp16)
    const int t    = threadIdx.x;
    const int w    = t >> 6;        // wave 0..3: cells [32w, 32w+32)
    const int lane = t & 63;
    const int q    = lane >> 4;     // A k-slice / replica selector
    const int n    = lane & 15;     // C/D column = cell-within-tile
    const int tile = q >> 1;        // this lane's cell tile (0,0,1,1)
    const int j    = 32 * w + 16 * tile + n;   // this lane's cell (2x replicated)
    const bool writer = ((q & 1) == 0);        // one replica writes

    // ---- B-fragments (weights) pinned to AGPRs: bw[tl][g][kt], 128 AGPRs
    f16x8 bw[2][4][4];
    {
        const f32x4* wp4 = (const f32x4*)whp;
        #pragma unroll
        for (int tl = 0; tl < 2; ++tl)
        #pragma unroll
        for (int g = 0; g < 4; ++g)
        #pragma unroll
        for (int kt = 0; kt < 4; ++kt) {
            frag_cast fc;
            fc.f = wp4[(((w * 2 + tl) * 4 + g) * 4 + kt) * 64 + lane];
            f16x8 tmp = fc.h;
            asm volatile("" : "=a"(bw[tl][g][kt]) : "0"(tmp));  // pin to AGPR class
        }
    }

    const f32x4 vzero = {0.f, 0.f, 0.f, 0.f};

    // h_{-1} = 0: zero hl[0] (128 halves = 64 dwords)
    if (t < 64) ((unsigned*)hl)[t] = 0u;

    // ---- xg prefetch: per-lane registers, 2-deep (xfA = even, xfB = odd)
    const float* xp = xg + j;
    float xfA[4], xfB[4];
    #pragma unroll
    for (int g = 0; g < 4; ++g) xfA[g] = xp[(size_t)0 * G4H + g * FDIM];
    #pragma unroll
    for (int g = 0; g < 4; ++g) xfB[g] = xp[(size_t)1 * G4H + g * FDIM];

    float c = 0.f;
    __syncthreads();   // hl[0] zeroed visible to all

#define LSTM_STEP18(STEP_T, XF)                                               \
{                                                                             \
    const int buf = (STEP_T) & 1;                                             \
    /* A-fragments: h[32kt+8q .. +8) broadcast (n-independent address) */     \
    f16x8 ah[4];                                                              \
    _Pragma("unroll")                                                         \
    for (int kt = 0; kt < 4; ++kt) {                                          \
        frag_cast fc;                                                         \
        fc.f = *(const f32x4*)((const char*)hl[buf] + kt * 64 + q * 16);      \
        ah[kt] = fc.h;                                                        \
    }                                                                         \
    /* 32 MFMAs: 2 tiles x 4 gates, depth-4 chains */                         \
    f32x4 cd[2][4];                                                           \
    _Pragma("unroll")                                                         \
    for (int tl = 0; tl < 2; ++tl)                                            \
    _Pragma("unroll")                                                         \
    for (int g = 0; g < 4; ++g)                                               \
        cd[tl][g] = __builtin_amdgcn_mfma_f32_16x16x32_f16(ah[0],             \
                        bw[tl][g][0], vzero, 0, 0, 0);                        \
    _Pragma("unroll")                                                         \
    for (int kt = 1; kt < 4; ++kt)                                            \
    _Pragma("unroll")                                                         \
    for (int tl = 0; tl < 2; ++tl)                                            \
    _Pragma("unroll")                                                         \
    for (int g = 0; g < 4; ++g)                                               \
        cd[tl][g] = __builtin_amdgcn_mfma_f32_16x16x32_f16(ah[kt],            \
                        bw[tl][g][kt], cd[tl][g], 0, 0, 0);                   \
    /* lane-local gates: rows identical, pick .x; 1 cndmask per gate */       \
    float gi = (tile ? cd[1][0].x : cd[0][0].x) + XF[0];                      \
    float gf = (tile ? cd[1][1].x : cd[0][1].x) + XF[1];                      \
    float gg = (tile ? cd[1][2].x : cd[0][2].x) + XF[2];                      \
    float go = (tile ? cd[1][3].x : cd[0][3].x) + XF[3];                      \
    gi = 1.f / (1.f + __expf(-gi));                                           \
    gf = 1.f / (1.f + __expf(-gf));                                           \
    gg = 1.f - 2.f / (1.f + __expf(2.f * gg));                                \
    go = 1.f / (1.f + __expf(-go));                                           \
    c = gf * c + gi * gg;                                                     \
    float th = 1.f - 2.f / (1.f + __expf(2.f * c));                           \
    float h = go * th;                                                        \
    if (writer) {                                                             \
        hl[buf ^ 1][j] = __float2half(h);                                     \
        hs[(size_t)(STEP_T) * FDIM + j] = h;   /* store: never waited on */   \
    }                                                                         \
    /* prefetch step+2 into the slot just consumed */                         \
    { int pid = (STEP_T) + 2; if (pid >= T) pid = T - 1;                      \
      const float* pp = xp + (size_t)pid * G4H;                               \
      _Pragma("unroll")                                                       \
      for (int g = 0; g < 4; ++g) XF[g] = pp[g * FDIM]; }                     \
    LDS_BARRIER();   /* the ONLY barrier: h(buf^1) visible for next step */   \
}

    for (int step = 0; step + 1 < T; step += 2) {
        LSTM_STEP18(step, xfA);
        LSTM_STEP18(step + 1, xfB);
    }
    if (T & 1) { LSTM_STEP18(T - 1, xfA); }
#undef LSTM_STEP18
}

// ---------------------------------------------------------------------------
// out[M x 12] = hs[M x 128] @ w_fc^T + b_fc
// ---------------------------------------------------------------------------
__global__ __launch_bounds__(256) void fc_kernel(const float* __restrict__ hs,
                                                 const float* __restrict__ wfc,
                                                 const float* __restrict__ bfc,
                                                 float* __restrict__ out, int M) {
    __shared__ float wl[12 * FDIM];
    __shared__ float bl[12];
    const int tid = threadIdx.x;
    for (int i = tid; i < 12 * FDIM / 4; i += 256)
        ((float4*)wl)[i] = ((const float4*)wfc)[i];
    if (tid < 12) bl[tid] = bfc[tid];
    __syncthreads();

    int i = blockIdx.x * 256 + tid;
    if (i >= M) return;
    const float* hrow = hs + (size_t)i * FDIM;
    float acc[12];
    #pragma unroll
    for (int t = 0; t < 12; ++t) acc[t] = bl[t];
    for (int k = 0; k < FDIM; k += 4) {
        float4 h4 = *(const float4*)(hrow + k);
        #pragma unroll
        for (int t = 0; t < 12; ++t) {
            acc[t] += h4.x * wl[t * FDIM + k] + h4.y * wl[t * FDIM + k + 1]
                    + h4.z * wl[t * FDIM + k + 2] + h4.w * wl[t * FDIM + k + 3];
        }
    }
    #pragma unroll
    for (int t = 0; t < 12; ++t) out[(size_t)i * 12 + t] = acc[t];
}

// ---------------------------------------------------------------------------
extern "C" void kernel_launch(void* const* d_in, const int* in_sizes, int n_in,
                              void* d_out, int out_size, void* d_ws, size_t ws_size,
                              hipStream_t stream) {
    const float* x    = (const float*)d_in[0];
    const int*   ei   = (const int*)  d_in[1];
    const float* W1   = (const float*)d_in[2];
    const float* b1   = (const float*)d_in[3];
    const float* W2   = (const float*)d_in[4];
    const float* b2   = (const float*)d_in[5];
    const float* w_ih = (const float*)d_in[6];
    const float* w_hh = (const float*)d_in[7];
    const float* b_ih = (const float*)d_in[8];
    const float* b_hh = (const float*)d_in[9];
    const float* w_fc = (const float*)d_in[10];
    const float* b_fc = (const float*)d_in[11];

    const int N = in_sizes[0] / FDIM;     // 20000
    const int E = in_sizes[1] / 2;        // 1280000

    float* ws   = (float*)d_ws;
    int*   deg  = (int*)ws;                       // 20480 ints
    float* dinv = ws + 20480;                     // 20480 floats
    float* whp  = ws + 40960;                     // 32768 dwords (packed fragments)
    int*   rs   = (int*)(ws + 73728);             // 20992 ints (N+1 used)
    int*   cur  = (int*)(ws + 94720);             // 20480 ints
    int*   csr  = (int*)(ws + 115200);            // E ints
    float* hB   = ws + 115200 + 1280000;          // N*128
    float* big  = hB + (size_t)N * FDIM;          // xg region (N*512), aliases y/hA
    float* y    = big;                            // N*128 (dead before xg written)
    float* hA   = big + (size_t)N * FDIM;         // h1   (dead before xg written)
    float* xg   = big;                            // N*512 ([step][gate*128+j])
    float* hs   = big + (size_t)N * G4H;          // N*128

    hipMemsetAsync(deg, 0, (size_t)N * sizeof(int), stream);
    deg_kernel<<<(E + 255) / 256, 256, 0, stream>>>(ei, deg, E);
    dinv_kernel<<<(N + 255) / 256, 256, 0, stream>>>(deg, dinv, N);
    scan_kernel<<<1, 1024, 0, stream>>>(deg, rs, cur, N, E);
    scatter_kernel<<<(E + 255) / 256, 256, 0, stream>>>(ei, cur, csr, E);
    pack_whh<<<(32768 + 255) / 256, 256, 0, stream>>>(w_hh, whp, 32768);

    const int gblocks = (N + 31) / 32;
    const int ablocks = (N + 3) / 4;
    // layer 1
    gemm_nn<<<gblocks, 256, 0, stream>>>(x, W1, y, N);
    agg_gather<<<ablocks, 256, 0, stream>>>(y, rs, csr, dinv, b1, hA, N);
    // layer 2
    gemm_nn<<<gblocks, 256, 0, stream>>>(hA, W2, y, N);
    agg_gather<<<ablocks, 256, 0, stream>>>(y, rs, csr, dinv, b2, hB, N);
    // LSTM input projection
    gemm_nt_xg<<<dim3(gblocks, 4), 256, 0, stream>>>(hB, w_ih, b_ih, b_hh, xg, N);
    // sequential LSTM (single CU — the critical path), v18: 4 waves, A/B swap
    lstm_kernel<<<1, 256, 0, stream>>>(xg, whp, hs, N);
    // final projection
    fc_kernel<<<(N + 255) / 256, 256, 0, stream>>>(hs, w_fc, b_fc, (float*)d_out, N);
}